// Round 14
// baseline (1228.928 us; speedup 1.0000x reference)
//
#include <hip/hip_runtime.h>
#include <hip/hip_bf16.h>

#define B_   2048
#define V_   1024
#define H_   512
#define E_   256
#define L_   32

typedef __attribute__((ext_vector_type(4))) float f32x4;
typedef unsigned short u16;
typedef unsigned int   u32;
typedef unsigned char  u8;
typedef unsigned long long u64;
typedef long long      i64;

__device__ __forceinline__ u32 f32b(float x){ union{float f;u32 u;}v; v.f=x; return v.u; }
__device__ __forceinline__ float bf32(u32 u){ union{float f;u32 u;}v; v.u=u; return v.f; }
__device__ __forceinline__ u16 f2bf(float x) {
    u32 u = f32b(x);
    u32 r = u + 0x7fffu + ((u >> 16) & 1u);
    return (u16)(r >> 16);
}
// OCP e4m3fn encode, RNE, flush below 2^-6
__device__ __forceinline__ u8 f2e4m3(float x) {
    u32 u = f32b(x);
    u32 s = (u >> 24) & 0x80u;
    u32 a = u & 0x7fffffffu;
    if (a < 0x3c800000u) return (u8)s;
    if (a > 0x43e00000u) a = 0x43e00000u;
    u32 r = a + 0x000fffffu + ((a >> 20) & 1u);
    if (r > 0x43e00000u) r = 0x43e00000u;
    u32 ex = (r >> 23) - 120u;
    u32 mn = (r >> 20) & 7u;
    return (u8)(s | (ex << 3) | mn);
}
__device__ __forceinline__ u8 f2fp8(float x) {
#if __has_builtin(__builtin_amdgcn_cvt_pk_fp8_f32)
    return (u8)(__builtin_amdgcn_cvt_pk_fp8_f32(x, x, 0, false) & 0xff);
#else
    return f2e4m3(x);
#endif
}
__device__ __forceinline__ float sig_(float x)  { return 1.f / (1.f + __expf(-x)); }
__device__ __forceinline__ float tanh_(float x) { return 1.f - 2.f / (__expf(2.f * x) + 1.f); }

__device__ __forceinline__ void ag_st64(void* p, u64 v) {
    __hip_atomic_store((u64*)p, v, __ATOMIC_RELAXED, __HIP_MEMORY_SCOPE_AGENT);
}
__device__ __forceinline__ u64 ag_ld64(const void* p) {
    return __hip_atomic_load((const u64*)p, __ATOMIC_RELAXED, __HIP_MEMORY_SCOPE_AGENT);
}
__device__ __forceinline__ void ag_st32(void* p, u32 v) {
    __hip_atomic_store((u32*)p, v, __ATOMIC_RELAXED, __HIP_MEMORY_SCOPE_AGENT);
}
__device__ __forceinline__ u32 ag_ld32(const void* p) {
    return __hip_atomic_load((const u32*)p, __ATOMIC_RELAXED, __HIP_MEMORY_SCOPE_AGENT);
}

// -------------------------------------------------------------------------
// 4-way gang layouts, all fp8 e4m3 x64. Chunk = 8 KB = 8 waves x 1 KB;
// wave's 1 KB = 2 frags x 512 B. Block qb of a 4-gang owns:
//  w1f[qb]: gate rows j in [qb*128,+128): [qb 4][ks2 12][g 4][wv 8][s 2][l 64][e 8]
//      k = (2*ks2+s)*32+(l>>4)*8+e,  n = g*512 + qb*128 + wv*16 + (l&15)
//  wof[qb]: logits v in [qb*256,+256): [qb 4][ks 16][wv 8][jv 2][l 64][e 8]
//      k = ks*32+(l>>4)*8+e,  v = qb*256 + wv*32 + jv*16 + (l&15)
//  wef[qb]: K-quarter (vocab) [qb*256,+256): [qb 4][ksp 8][wv 8][jc 2][l 64][e 8]
//      kv = qb*256 + ksp*32+(l>>4)*8+e,  ce = wv*32 + jc*16 + (l&15)
// -------------------------------------------------------------------------
__global__ void prep(const float* __restrict__ W_ih, const float* __restrict__ W_hh,
                     const float* __restrict__ b_ih, const float* __restrict__ b_hh,
                     const float* __restrict__ W_out, const float* __restrict__ W_emb,
                     u8* __restrict__ w1f, u8* __restrict__ wof, u8* __restrict__ wef,
                     float* __restrict__ b1, u32* __restrict__ flg)
{
    u32 idx = blockIdx.x * 256 + threadIdx.x;
    if (idx < 1572864u) {                      // W1 quarters -> fp8*64
        u32 qb = idx / 393216u;
        u32 r1 = idx - qb * 393216u;
        u32 ks2 = r1 >> 15;                    // 0..11
        u32 r2 = r1 & 32767u;
        u32 g = r2 >> 13, wv = (r2 >> 10) & 7u, s = (r2 >> 9) & 1u,
            l = (r2 >> 3) & 63u, e = r2 & 7u;
        u32 k = (2u * ks2 + s) * 32u + ((l >> 4) << 3) + e;
        u32 n = g * 512u + qb * 128u + wv * 16u + (l & 15u);
        float v = (k < E_) ? W_ih[n * E_ + k] : W_hh[n * H_ + (k - E_)];
        w1f[idx] = f2e4m3(v * 64.f);
    } else if (idx < 2097152u) {               // W_out quarters -> fp8*64
        u32 j = idx - 1572864u;
        u32 qb = j >> 17;
        u32 rem = j & 131071u;
        u32 ks = rem >> 13, wv = (rem >> 10) & 7u, jv = (rem >> 9) & 1u,
            l = (rem >> 3) & 63u, e = rem & 7u;
        u32 k = ks * 32u + ((l >> 4) << 3) + e;
        u32 v = qb * 256u + wv * 32u + jv * 16u + (l & 15u);
        wof[j] = f2e4m3(W_out[v * H_ + k] * 64.f);
    } else if (idx < 2359296u) {               // W_emb K-quarters -> fp8*64
        u32 j = idx - 2097152u;
        u32 qb = j >> 16;
        u32 rem = j & 65535u;
        u32 ksp = rem >> 13, wv = (rem >> 10) & 7u, jc = (rem >> 9) & 1u,
            l = (rem >> 3) & 63u, e = rem & 7u;
        u32 kv = qb * 256u + ksp * 32u + ((l >> 4) << 3) + e;
        u32 ce = wv * 32u + jc * 16u + (l & 15u);
        wef[j] = f2e4m3(W_emb[ce * V_ + kv] * 64.f);
    } else if (idx < 2361344u) {
        u32 j = idx - 2359296u;
        b1[j] = b_ih[j] + b_hh[j];
    } else if (idx < 2365440u) {
        flg[idx - 2361344u] = 0u;              // re-arm gang barriers each run
    }
}

// LDS layout (bytes)
#define RING  0u        // 12 slots x 8192
#define AEO   98304u    // 32 x 776 fp8: [0,256) e*16, [256,768) h*16 (full)
#define XSO   123136u   // 32 x 264 fp8 xs-quarter = exp(z-m_loc)*256
#define RMX   131584u   // 32 rows x 8 waves f32
#define RSM   132608u   // 32 rows x 8 waves f32
#define LDS_TOTAL 133632

#define WAITVM_(N) asm volatile("s_waitcnt vmcnt(" #N ")" ::: "memory")
#define WAITVM(N) WAITVM_(N)

typedef const __attribute__((address_space(1))) void* gvp;
typedef __attribute__((address_space(3))) void* svp;

__global__ __launch_bounds__(512, 2)
void lstm_fused(const float* __restrict__ x, const float* __restrict__ gum,
                const u8* __restrict__ w1f, const u8* __restrict__ wof,
                const u8* __restrict__ wef, const float* __restrict__ b1,
                const float* __restrict__ b_out, const float* __restrict__ b_emb,
                const float* __restrict__ sos, float* __restrict__ out,
                u8* __restrict__ hx, char* __restrict__ ms, char* __restrict__ ep,
                u32* __restrict__ flg)
{
    extern __shared__ char smem[];

    const u32 tid = threadIdx.x;
    const u32 w   = tid >> 6;        // wave 0..7
    const u32 l   = tid & 63u;
    const u32 q   = l >> 4;
    const u32 col = l & 15u;

    const u32 bid = blockIdx.x;
    const u32 p   = bid & 63u;       // gang id (32 rows)
    const u32 qb  = bid >> 6;        // quarter 0..3 (gang members share an XCD)
    const u32 q1  = (qb + 1u) & 3u, q2 = (qb + 2u) & 3u, q3 = (qb + 3u) & 3u;
    const int r0  = (int)(p << 5);

    u32* myf = flg + p * 64u + qb * 16u;
    u32* pf0 = flg + p * 64u + q1 * 16u;
    u32* pf1 = flg + p * 64u + q2 * 16u;
    u32* pf2 = flg + p * 64u + q3 * 16u;
    u32 nbar = 0;

    const u32 wK = w << 10, lB = l << 4, l8 = l << 3, q8 = q << 3;
    const char* w1q = (const char*)w1f + (size_t)qb * 393216u;
    const char* woq = (const char*)wof + (size_t)qb * 131072u;
    const char* weq = (const char*)wef + (size_t)qb * 65536u;

#define PBAR() do { WAITVM(0); __syncthreads(); \
    if (tid == 0) { \
        __hip_atomic_fetch_add(myf, 1u, __ATOMIC_RELAXED, __HIP_MEMORY_SCOPE_AGENT); \
        for (;;) { \
            u32 _a = __hip_atomic_load(pf0, __ATOMIC_RELAXED, __HIP_MEMORY_SCOPE_AGENT); \
            u32 _b = __hip_atomic_load(pf1, __ATOMIC_RELAXED, __HIP_MEMORY_SCOPE_AGENT); \
            u32 _c = __hip_atomic_load(pf2, __ATOMIC_RELAXED, __HIP_MEMORY_SCOPE_AGENT); \
            if (_a >= nbar && _b >= nbar && _c >= nbar) break; \
            __builtin_amdgcn_s_sleep(2); \
        } \
    } \
    __syncthreads(); } while (0)

// issue chunk C (byte GOFF in BASE) into ring slot byte SOFF (1 KB wave slice)
#define ISSR(BASE, GOFF, SOFF) do { \
    u32 _o = (u32)__builtin_amdgcn_readfirstlane((int)((SOFF) + wK)); \
    __builtin_amdgcn_global_load_lds((gvp)((BASE) + (size_t)(GOFF) + wK + lB), \
                                     (svp)(smem + _o), 16, 0, 0); } while (0)
#define ISSL(BASE, C, SLOT) ISSR(BASE, (u32)(C) * 8192u, (u32)(SLOT) * 8192u)

// A consume: chunk (ks2,g) at slot byte SB; a8[s][rt]
#define CONSA(G, SB, A00, A10, A01, A11) { \
    const char* _fb = smem + (SB) + wK + l8; \
    i64 _f0 = *(const i64*)(_fb); i64 _f1 = *(const i64*)(_fb + 512u); \
    acc[G][0] = __builtin_amdgcn_mfma_f32_16x16x32_fp8_fp8(A00, _f0, acc[G][0], 0, 0, 0); \
    acc[G][0] = __builtin_amdgcn_mfma_f32_16x16x32_fp8_fp8(A10, _f1, acc[G][0], 0, 0, 0); \
    acc[G][1] = __builtin_amdgcn_mfma_f32_16x16x32_fp8_fp8(A01, _f0, acc[G][1], 0, 0, 0); \
    acc[G][1] = __builtin_amdgcn_mfma_f32_16x16x32_fp8_fp8(A11, _f1, acc[G][1], 0, 0, 0); }

// B consume: chunk ks at slot SB; a8 per rt
#define CONSB(SB, A0, A1) { \
    const char* _fb = smem + (SB) + wK + l8; \
    i64 _g0 = *(const i64*)(_fb); i64 _g1 = *(const i64*)(_fb + 512u); \
    accB[0][0] = __builtin_amdgcn_mfma_f32_16x16x32_fp8_fp8(A0, _g0, accB[0][0], 0, 0, 0); \
    accB[1][0] = __builtin_amdgcn_mfma_f32_16x16x32_fp8_fp8(A0, _g1, accB[1][0], 0, 0, 0); \
    accB[0][1] = __builtin_amdgcn_mfma_f32_16x16x32_fp8_fp8(A1, _g0, accB[0][1], 0, 0, 0); \
    accB[1][1] = __builtin_amdgcn_mfma_f32_16x16x32_fp8_fp8(A1, _g1, accB[1][1], 0, 0, 0); }

// C consume: chunk ksp at slot SB; xs a8 per rt
#define CONSC(SB, X0, X1) { \
    const char* _fb = smem + (SB) + wK + l8; \
    i64 _g0 = *(const i64*)(_fb); i64 _g1 = *(const i64*)(_fb + 512u); \
    accC[0][0] = __builtin_amdgcn_mfma_f32_16x16x32_fp8_fp8(X0, _g0, accC[0][0], 0, 0, 0); \
    accC[1][0] = __builtin_amdgcn_mfma_f32_16x16x32_fp8_fp8(X0, _g1, accC[1][0], 0, 0, 0); \
    accC[0][1] = __builtin_amdgcn_mfma_f32_16x16x32_fp8_fp8(X1, _g0, accC[0][1], 0, 0, 0); \
    accC[1][1] = __builtin_amdgcn_mfma_f32_16x16x32_fp8_fp8(X1, _g1, accC[1][1], 0, 0, 0); }

#define BA8(KS, RT) (*(const i64*)(smem + AEO + (((RT)*16u + col) * 776u) + 256u + ((u32)(KS) << 5) + q8))
#define XA8(KSP, RT) (*(const i64*)(smem + XSO + (((RT)*16u + col) * 264u) + ((u32)(KSP) << 5) + q8))

    // EOS v-quarter
    for (u32 i = tid; i < 32u * 256u; i += 512u) {
        u32 row = i >> 8, vl = i & 255u;
        __builtin_nontemporal_store((qb == 0u && vl == 0u) ? 1.f : 0.f,
            &out[((size_t)(r0 + (int)row) * 33 + 32) * V_ + qb * 256u + vl]);
    }
    // e0 = sos*16 (full), h0 = x*16 (full)
    for (u32 i = tid; i < 32u * 256u; i += 512u) {
        u32 row = i >> 8, k = i & 255u;
        *(u8*)(smem + AEO + row * 776u + k) = f2fp8(sos[k] * 16.f);
    }
    for (u32 i = tid; i < 32u * 512u; i += 512u) {
        u32 row = i >> 9, k = i & 511u;
        *(u8*)(smem + AEO + row * 776u + 256u + k) = f2fp8(x[(r0 + (int)(row)) * H_ + k] * 16.f);
    }

    // biases (own quarters); per thread one gate column
    const u32 jg = qb * 128u + (w << 4) + col;
    const float bi_ = b1[jg],            bf_ = b1[H_ + jg],
                bg_ = b1[2 * H_ + jg],   bo_ = b1[3 * H_ + jg];
    float bov[2], bem16[2];
    #pragma unroll
    for (int jv = 0; jv < 2; ++jv)
        bov[jv] = b_out[qb * 256u + (w << 5) + (u32)jv * 16u + col];
    #pragma unroll
    for (int jc = 0; jc < 2; ++jc)
        bem16[jc] = b_emb[(w << 5) + (u32)jc * 16u + col] * 16.f;

    float creg[2][4];
    #pragma unroll
    for (int rt = 0; rt < 2; ++rt)
        #pragma unroll
        for (int r = 0; r < 4; ++r) creg[rt][r] = 0.f;

    __syncthreads();

    const f32x4 fz = {0.f, 0.f, 0.f, 0.f};
    const float S1 = 1.f / 1024.f;

    // A prologue for t=0 (chunks 0..10)
    ISSL(w1q, 0, 0);  ISSL(w1q, 1, 1);  ISSL(w1q, 2, 2);  ISSL(w1q, 3, 3);
    ISSL(w1q, 4, 4);  ISSL(w1q, 5, 5);  ISSL(w1q, 6, 6);  ISSL(w1q, 7, 7);
    ISSL(w1q, 8, 8);  ISSL(w1q, 9, 9);  ISSL(w1q, 10, 10);

    #pragma unroll 1
    for (int t = 0; t < L_; ++t) {
        // ====== phase A: gate-quarter, ring-12 (48 chunks) ======
        f32x4 acc[4][2];
        #pragma unroll
        for (int g = 0; g < 4; ++g) { acc[g][0] = fz; acc[g][1] = fz; }

        u32 co = 0, io = 90112u, gio = 90112u;
        #pragma unroll 1
        for (u32 ks2 = 0; ks2 < 9; ++ks2) {
            u32 ab = AEO + col * 776u + (ks2 << 6);
            i64 a00 = *(const i64*)(smem + ab + q8);
            i64 a10 = *(const i64*)(smem + ab + 32u + q8);
            i64 a01 = *(const i64*)(smem + ab + 12416u + q8);         // +16*776
            i64 a11 = *(const i64*)(smem + ab + 12416u + 32u + q8);
            #pragma unroll
            for (int g = 0; g < 4; ++g) {
                WAITVM(10);
                CONSA(g, co, a00, a10, a01, a11);
                ISSR(w1q, gio, io);
                co += 8192u; if (co == 98304u) co = 0u;
                io += 8192u; if (io == 98304u) io = 0u;
                gio += 8192u;
            }
        }
        {   // ks2 = 9: chunks 36..39 (slots 0..3); last issue chunk 47 (slot 11)
            u32 ab = AEO + col * 776u + (9u << 6);
            i64 a00 = *(const i64*)(smem + ab + q8);
            i64 a10 = *(const i64*)(smem + ab + 32u + q8);
            i64 a01 = *(const i64*)(smem + ab + 12416u + q8);
            i64 a11 = *(const i64*)(smem + ab + 12416u + 32u + q8);
            WAITVM(10); CONSA(0, 0u,      a00, a10, a01, a11); ISSL(w1q, 47, 11);
            WAITVM(10); CONSA(1, 8192u,   a00, a10, a01, a11);
            WAITVM(9);  CONSA(2, 16384u,  a00, a10, a01, a11);
            WAITVM(8);  CONSA(3, 24576u,  a00, a10, a01, a11);
        }
        {   // ks2 = 10: chunks 40..43 (slots 4..7)
            u32 ab = AEO + col * 776u + (10u << 6);
            i64 a00 = *(const i64*)(smem + ab + q8);
            i64 a10 = *(const i64*)(smem + ab + 32u + q8);
            i64 a01 = *(const i64*)(smem + ab + 12416u + q8);
            i64 a11 = *(const i64*)(smem + ab + 12416u + 32u + q8);
            WAITVM(7); CONSA(0, 32768u, a00, a10, a01, a11);
            WAITVM(6); CONSA(1, 40960u, a00, a10, a01, a11);
            WAITVM(5); CONSA(2, 49152u, a00, a10, a01, a11);
            WAITVM(4); CONSA(3, 57344u, a00, a10, a01, a11);
        }
        {   // ks2 = 11: chunks 44..47 (slots 8..11)
            u32 ab = AEO + col * 776u + (11u << 6);
            i64 a00 = *(const i64*)(smem + ab + q8);
            i64 a10 = *(const i64*)(smem + ab + 32u + q8);
            i64 a01 = *(const i64*)(smem + ab + 12416u + q8);
            i64 a11 = *(const i64*)(smem + ab + 12416u + 32u + q8);
            WAITVM(3); CONSA(0, 65536u, a00, a10, a01, a11);
            WAITVM(2); CONSA(1, 73728u, a00, a10, a01, a11);
            WAITVM(1); CONSA(2, 81920u, a00, a10, a01, a11);
            WAITVM(0); CONSA(3, 90112u, a00, a10, a01, a11);
        }
        __syncthreads();            // AEO reads done before h overwrite

        // LSTM pointwise (own j-quarter)
        #pragma unroll
        for (int rt = 0; rt < 2; ++rt)
            #pragma unroll
            for (int r = 0; r < 4; ++r) {
                float gi = sig_(acc[0][rt][r] * S1 + bi_);
                float gf = sig_(acc[1][rt][r] * S1 + bf_);
                float gg = tanh_(acc[2][rt][r] * S1 + bg_);
                float go = sig_(acc[3][rt][r] * S1 + bo_);
                float c  = gf * creg[rt][r] + gi * gg;
                creg[rt][r] = c;
                float h = go * tanh_(c);
                u32 row = ((u32)rt << 4) + (q << 2) + (u32)r;
                *(u8*)(smem + AEO + row * 776u + 256u + jg) = f2fp8(h * 16.f);
            }
        __syncthreads();            // own h-quarter complete in AEO

        // export own h-quarter; B-prologue + gumbel hide under barrier 1
        {   u32 row = tid >> 4, off = (tid & 15u) << 3;
            u64 v = *(const u64*)(smem + AEO + row * 776u + 256u + qb * 128u + off);
            ag_st64(hx + (size_t)p * 16384u + qb * 4096u + row * 128u + off, v);
        }
        ISSL(woq, 0, 0);  ISSL(woq, 1, 1);  ISSL(woq, 2, 2);  ISSL(woq, 3, 3);
        ISSL(woq, 4, 4);  ISSL(woq, 5, 5);  ISSL(woq, 6, 6);  ISSL(woq, 7, 7);
        ISSL(woq, 8, 8);  ISSL(woq, 9, 9);  ISSL(woq, 10, 10);
        const float* gt = gum + (size_t)t * (B_ * V_) + (size_t)r0 * V_;
        float gr[2][2][4];          // [jv][rt][r]
        #pragma unroll
        for (int jv = 0; jv < 2; ++jv)
            #pragma unroll
            for (int rt = 0; rt < 2; ++rt) {
                u32 vg = qb * 256u + (w << 5) + (u32)jv * 16u + col;
                #pragma unroll
                for (int r = 0; r < 4; ++r) {
                    u32 row = ((u32)rt << 4) + (q << 2) + (u32)r;
                    gr[jv][rt][r] = __builtin_nontemporal_load(&gt[row * V_ + vg]);
                }
            }
        ++nbar; PBAR();             // barrier 1: peer h ready

        // import 3 peer h-quarters
        {   u32 row = tid >> 4, off = (tid & 15u) << 3;
            u64 v1 = ag_ld64(hx + (size_t)p * 16384u + q1 * 4096u + row * 128u + off);
            u64 v2 = ag_ld64(hx + (size_t)p * 16384u + q2 * 4096u + row * 128u + off);
            u64 v3 = ag_ld64(hx + (size_t)p * 16384u + q3 * 4096u + row * 128u + off);
            *(u64*)(smem + AEO + row * 776u + 256u + q1 * 128u + off) = v1;
            *(u64*)(smem + AEO + row * 776u + 256u + q2 * 128u + off) = v2;
            *(u64*)(smem + AEO + row * 776u + 256u + q3 * 128u + off) = v3;
        }
        __syncthreads();            // full h in AEO

        // ====== phase B: logit v-quarter, ring-12 (16 chunks) ======
        f32x4 accB[2][2];           // [jv][rt]
        accB[0][0] = fz; accB[0][1] = fz; accB[1][0] = fz; accB[1][1] = fz;
        { i64 a0 = BA8(0,0),  a1 = BA8(0,1);  WAITVM(10); CONSB(0u,      a0, a1); ISSL(woq, 11, 11); }
        { i64 a0 = BA8(1,0),  a1 = BA8(1,1);  WAITVM(10); CONSB(8192u,   a0, a1); ISSL(woq, 12, 0); }
        { i64 a0 = BA8(2,0),  a1 = BA8(2,1);  WAITVM(10); CONSB(16384u,  a0, a1); ISSL(woq, 13, 1); }
        { i64 a0 = BA8(3,0),  a1 = BA8(3,1);  WAITVM(10); CONSB(24576u,  a0, a1); ISSL(woq, 14, 2); }
        { i64 a0 = BA8(4,0),  a1 = BA8(4,1);  WAITVM(10); CONSB(32768u,  a0, a1); ISSL(woq, 15, 3); }
        { i64 a0 = BA8(5,0),  a1 = BA8(5,1);  WAITVM(10); CONSB(40960u,  a0, a1); }
        { i64 a0 = BA8(6,0),  a1 = BA8(6,1);  WAITVM(9);  CONSB(49152u,  a0, a1); }
        { i64 a0 = BA8(7,0),  a1 = BA8(7,1);  WAITVM(8);  CONSB(57344u,  a0, a1); }
        { i64 a0 = BA8(8,0),  a1 = BA8(8,1);  WAITVM(7);  CONSB(65536u,  a0, a1); }
        { i64 a0 = BA8(9,0),  a1 = BA8(9,1);  WAITVM(6);  CONSB(73728u,  a0, a1); }
        { i64 a0 = BA8(10,0), a1 = BA8(10,1); WAITVM(5);  CONSB(81920u,  a0, a1); }
        { i64 a0 = BA8(11,0), a1 = BA8(11,1); WAITVM(4);  CONSB(90112u,  a0, a1); }
        { i64 a0 = BA8(12,0), a1 = BA8(12,1); WAITVM(3);  CONSB(0u,      a0, a1); }
        { i64 a0 = BA8(13,0), a1 = BA8(13,1); WAITVM(2);  CONSB(8192u,   a0, a1); }
        { i64 a0 = BA8(14,0), a1 = BA8(14,1); WAITVM(1);  CONSB(16384u,  a0, a1); }
        { i64 a0 = BA8(15,0), a1 = BA8(15,1); WAITVM(0);  CONSB(24576u,  a0, a1); }

        // z; LOCAL (quarter) max
        float m_loc[2][4], s_loc[2][4];
        #pragma unroll
        for (int rt = 0; rt < 2; ++rt)
            #pragma unroll
            for (int r = 0; r < 4; ++r) m_loc[rt][r] = -1e30f;
        #pragma unroll
        for (int jv = 0; jv < 2; ++jv)
            #pragma unroll
            for (int rt = 0; rt < 2; ++rt)
                #pragma unroll
                for (int r = 0; r < 4; ++r) {
                    float zz = accB[jv][rt][r] * S1 + bov[jv] + gr[jv][rt][r];
                    accB[jv][rt][r] = zz;
                    m_loc[rt][r] = fmaxf(m_loc[rt][r], zz);
                }
        #pragma unroll
        for (int m = 1; m < 16; m <<= 1)
            #pragma unroll
            for (int rt = 0; rt < 2; ++rt)
                #pragma unroll
                for (int r = 0; r < 4; ++r)
                    m_loc[rt][r] = fmaxf(m_loc[rt][r], __shfl_xor(m_loc[rt][r], m, 64));
        if (col == 0) {
            #pragma unroll
            for (int rt = 0; rt < 2; ++rt)
                #pragma unroll
                for (int r = 0; r < 4; ++r) {
                    u32 row = ((u32)rt << 4) + (q << 2) + (u32)r;
                    *(float*)(smem + RMX + (row * 8u + w) * 4u) = m_loc[rt][r];
                }
        }
        __syncthreads();
        #pragma unroll
        for (int rt = 0; rt < 2; ++rt)
            #pragma unroll
            for (int r = 0; r < 4; ++r) {
                u32 row = ((u32)rt << 4) + (q << 2) + (u32)r;
                float mm = -1e30f;
                #pragma unroll
                for (int ww = 0; ww < 8; ++ww)
                    mm = fmaxf(mm, *(const float*)(smem + RMX + (row * 8u + (u32)ww) * 4u));
                m_loc[rt][r] = mm;
            }
        // C-prologue hides under softmax (slots 0..7 free: B chunks consumed)
        ISSL(weq, 0, 0); ISSL(weq, 1, 1); ISSL(weq, 2, 2); ISSL(weq, 3, 3);
        ISSL(weq, 4, 4); ISSL(weq, 5, 5); ISSL(weq, 6, 6); ISSL(weq, 7, 7);
        // eb = exp(z - m_loc); local sum; xs-quarter (local scale)
        float ps[2][4];
        #pragma unroll
        for (int rt = 0; rt < 2; ++rt)
            #pragma unroll
            for (int r = 0; r < 4; ++r) ps[rt][r] = 0.f;
        #pragma unroll
        for (int jv = 0; jv < 2; ++jv)
            #pragma unroll
            for (int rt = 0; rt < 2; ++rt) {
                u32 vl = (w << 5) + (u32)jv * 16u + col;
                #pragma unroll
                for (int r = 0; r < 4; ++r) {
                    float Ee = __expf(accB[jv][rt][r] - m_loc[rt][r]);
                    accB[jv][rt][r] = Ee;
                    ps[rt][r] += Ee;
                    u32 row = ((u32)rt << 4) + (q << 2) + (u32)r;
                    *(u8*)(smem + XSO + row * 264u + vl) = f2fp8(Ee * 256.f);
                }
            }
        #pragma unroll
        for (int m = 1; m < 16; m <<= 1)
            #pragma unroll
            for (int rt = 0; rt < 2; ++rt)
                #pragma unroll
                for (int r = 0; r < 4; ++r)
                    ps[rt][r] += __shfl_xor(ps[rt][r], m, 64);
        if (col == 0) {
            #pragma unroll
            for (int rt = 0; rt < 2; ++rt)
                #pragma unroll
                for (int r = 0; r < 4; ++r) {
                    u32 row = ((u32)rt << 4) + (q << 2) + (u32)r;
                    *(float*)(smem + RSM + (row * 8u + w) * 4u) = ps[rt][r];
                }
        }
        __syncthreads();            // xs + RSM visible block-wide
        #pragma unroll
        for (int rt = 0; rt < 2; ++rt)
            #pragma unroll
            for (int r = 0; r < 4; ++r) {
                u32 row = ((u32)rt << 4) + (q << 2) + (u32)r;
                float ss = 0.f;
                #pragma unroll
                for (int ww = 0; ww < 8; ++ww)
                    ss += *(const float*)(smem + RSM + (row * 8u + (u32)ww) * 4u);
                s_loc[rt][r] = ss;
            }

        // ====== phase C: partial e (own K-quarter, LOCAL xs), 8 chunks ======
        f32x4 accC[2][2];           // [jc][rt]
        accC[0][0] = fz; accC[0][1] = fz; accC[1][0] = fz; accC[1][1] = fz;
        { i64 x0 = XA8(0,0), x1 = XA8(0,1); WAITVM(7); CONSC(0u,      x0, x1); }
        { i64 x0 = XA8(1,0), x1 = XA8(1,1); WAITVM(6); CONSC(8192u,   x0, x1); }
        { i64 x0 = XA8(2,0), x1 = XA8(2,1); WAITVM(5); CONSC(16384u,  x0, x1); }
        { i64 x0 = XA8(3,0), x1 = XA8(3,1); WAITVM(4); CONSC(24576u,  x0, x1); }
        { i64 x0 = XA8(4,0), x1 = XA8(4,1); WAITVM(3); CONSC(32768u,  x0, x1); }
        { i64 x0 = XA8(5,0), x1 = XA8(5,1); WAITVM(2); CONSC(40960u,  x0, x1); }
        { i64 x0 = XA8(6,0), x1 = XA8(6,1); WAITVM(1); CONSC(49152u,  x0, x1); }
        { i64 x0 = XA8(7,0), x1 = XA8(7,1); WAITVM(0); CONSC(57344u,  x0, x1); }

        // exports: (m,s) + UNNORMALIZED e-partials; A-prologue; barrier 2
        float part[2][2][4];        // [jc][rt][r]
        #pragma unroll
        for (int jc = 0; jc < 2; ++jc)
            #pragma unroll
            for (int rt = 0; rt < 2; ++rt)
                #pragma unroll
                for (int r = 0; r < 4; ++r)
                    part[jc][rt][r] = accC[jc][rt][r] * (16.f / 16384.f);
        if (w == 0 && col == 0) {
            #pragma unroll
            for (int rt = 0; rt < 2; ++rt)
                #pragma unroll
                for (int r = 0; r < 4; ++r) {
                    u32 row = ((u32)rt << 4) + (q << 2) + (u32)r;
                    u64 v = ((u64)f32b(s_loc[rt][r]) << 32) | (u64)f32b(m_loc[rt][r]);
                    ag_st64(ms + (size_t)p * 1024u + row * 32u + qb * 8u, v);
                }
        }
        #pragma unroll
        for (int rt = 0; rt < 2; ++rt)
            #pragma unroll
            for (int r = 0; r < 4; ++r) {
                u32 row = ((u32)rt << 4) + (q << 2) + (u32)r;
                u32 pv = (u32)f2bf(part[0][rt][r]) | ((u32)f2bf(part[1][rt][r]) << 16);
                ag_st32(ep + (size_t)p * 65536u + qb * 16384u + ((row * 8u + w) * 16u + col) * 4u, pv);
            }
        ISSL(w1q, 0, 0);  ISSL(w1q, 1, 1);  ISSL(w1q, 2, 2);  ISSL(w1q, 3, 3);
        ISSL(w1q, 4, 4);  ISSL(w1q, 5, 5);  ISSL(w1q, 6, 6);  ISSL(w1q, 7, 7);
        ISSL(w1q, 8, 8);  ISSL(w1q, 9, 9);  ISSL(w1q, 10, 10);
        ++nbar; PBAR();             // barrier 2: (m,s) + partials visible

        // global softmax factors + e-combine
        float foinv[2][4];
        #pragma unroll
        for (int rt = 0; rt < 2; ++rt)
            #pragma unroll
            for (int r = 0; r < 4; ++r) {
                u32 row = ((u32)rt << 4) + (q << 2) + (u32)r;
                u64 v1 = ag_ld64(ms + (size_t)p * 1024u + row * 32u + q1 * 8u);
                u64 v2 = ag_ld64(ms + (size_t)p * 1024u + row * 32u + q2 * 8u);
                u64 v3 = ag_ld64(ms + (size_t)p * 1024u + row * 32u + q3 * 8u);
                float m1 = bf32((u32)v1), s1 = bf32((u32)(v1 >> 32));
                float m2 = bf32((u32)v2), s2 = bf32((u32)(v2 >> 32));
                float m3 = bf32((u32)v3), s3 = bf32((u32)(v3 >> 32));
                float m0 = m_loc[rt][r], s0 = s_loc[rt][r];
                float mg = fmaxf(fmaxf(m0, m1), fmaxf(m2, m3));
                float f0 = __expf(m0 - mg), f1 = __expf(m1 - mg),
                      f2 = __expf(m2 - mg), f3 = __expf(m3 - mg);
                float inv = 1.f / (s0 * f0 + s1 * f1 + s2 * f2 + s3 * f3);
                foinv[rt][r] = f0 * inv;
                u32 eoff = ((row * 8u + w) * 16u + col) * 4u;
                u32 p1 = ag_ld32(ep + (size_t)p * 65536u + q1 * 16384u + eoff);
                u32 p2 = ag_ld32(ep + (size_t)p * 65536u + q2 * 16384u + eoff);
                u32 p3 = ag_ld32(ep + (size_t)p * 65536u + q3 * 16384u + eoff);
                #pragma unroll
                for (int jc = 0; jc < 2; ++jc) {
                    float e1 = bf32(((p1 >> (16 * jc)) & 0xffffu) << 16);
                    float e2 = bf32(((p2 >> (16 * jc)) & 0xffffu) << 16);
                    float e3 = bf32(((p3 >> (16 * jc)) & 0xffffu) << 16);
                    float e16 = (part[jc][rt][r] * f0 + e1 * f1 + e2 * f2 + e3 * f3) * inv
                                + bem16[jc];
                    *(u8*)(smem + AEO + row * 776u + (w << 5) + (u32)jc * 16u + col) = f2fp8(e16);
                }
            }
        // out v-quarter (fp32 eb still live in accB)
        #pragma unroll
        for (int jv = 0; jv < 2; ++jv)
            #pragma unroll
            for (int rt = 0; rt < 2; ++rt) {
                u32 vg = qb * 256u + (w << 5) + (u32)jv * 16u + col;
                #pragma unroll
                for (int r = 0; r < 4; ++r) {
                    u32 row = ((u32)rt << 4) + (q << 2) + (u32)r;
                    __builtin_nontemporal_store(accB[jv][rt][r] * foinv[rt][r],
                        &out[((size_t)(r0 + (int)row) * 33 + t) * V_ + vg]);
                }
            }
        __syncthreads();            // e complete before next step's phase A
    }
#undef PBAR
#undef ISSR
#undef ISSL
#undef CONSA
#undef CONSB
#undef CONSC
#undef BA8
#undef XA8
}

extern "C" void kernel_launch(void* const* d_in, const int* in_sizes, int n_in,
                              void* d_out, int out_size, void* d_ws, size_t ws_size,
                              hipStream_t stream) {
    const float* x     = (const float*)d_in[0];
    const float* gum   = (const float*)d_in[1];
    const float* W_ih  = (const float*)d_in[2];
    const float* W_hh  = (const float*)d_in[3];
    const float* b_ih  = (const float*)d_in[4];
    const float* b_hh  = (const float*)d_in[5];
    const float* W_out = (const float*)d_in[6];
    const float* b_out = (const float*)d_in[7];
    const float* W_emb = (const float*)d_in[8];
    const float* b_emb = (const float*)d_in[9];
    const float* sos   = (const float*)d_in[10];
    float* out = (float*)d_out;

    char* ws = (char*)d_ws;
    u8*    w1f = (u8*)(ws);                    // 1,572,864 B
    u8*    wof = (u8*)(ws + 1572864);          //   524,288 B
    u8*    wef = (u8*)(ws + 2097152);          //   262,144 B
    float* b1  = (float*)(ws + 2359296);       //     8,192 B
    u32*   flg = (u32*)(ws + 2367488);         //    16,384 B (gang barriers)
    u8*    hx  = (u8*)(ws + 2383872);          // 1,048,576 B (h exchange)
    char*  ms  = (char*)(ws + 3432448);        //    65,536 B (max/sum)
    char*  ep  = (char*)(ws + 3497984);        // 4,194,304 B (e partials)
    // total 7,692,288 B

    hipFuncSetAttribute((const void*)lstm_fused,
                        hipFuncAttributeMaxDynamicSharedMemorySize, LDS_TOTAL);

    prep<<<9240, 256, 0, stream>>>(W_ih, W_hh, b_ih, b_hh, W_out, W_emb,
                                   w1f, wof, wef, b1, flg);
    lstm_fused<<<256, 512, LDS_TOTAL, stream>>>(x, gum, w1f, wof, wef, b1,
                                                b_out, b_emb, sos, out,
                                                hx, ms, ep, flg);
}